// Round 18
// baseline (308.685 us; speedup 1.0000x reference)
//
#include <hip/hip_runtime.h>

#define R_    16
#define NBAS  30
#define DIN1  128
#define DHID  128
#define DOUT2 64
#define DADR  400
#define KCH   128              // feature width of both layer inputs
#define LDB   ((R_ + 1) * 128) // combined weight row length (16 relations + root)

typedef __attribute__((ext_vector_type(8))) short bf16x8;
typedef __attribute__((ext_vector_type(4))) float f32x4;

__device__ __forceinline__ short f2bf(float f) {
    unsigned u = __float_as_uint(f);
    u += 0x7fffu + ((u >> 16) & 1u);   // round-to-nearest-even
    return (short)(u >> 16);
}
__device__ __forceinline__ unsigned packbf(float lo, float hi) {
    return (unsigned)(unsigned short)f2bf(lo) | ((unsigned)(unsigned short)f2bf(hi) << 16);
}

struct Row8 { f32x4 lo, hi; };   // 8 channel accumulators (by value everywhere)

__device__ __forceinline__ Row8 row8_zero() {
    Row8 z; z.lo = (f32x4){0.f,0.f,0.f,0.f}; z.hi = (f32x4){0.f,0.f,0.f,0.f}; return z;
}
__device__ __forceinline__ Row8 row8_add(Row8 a, int4 v) {
    unsigned u0 = (unsigned)v.x, u1 = (unsigned)v.y, u2 = (unsigned)v.z, u3 = (unsigned)v.w;
    a.lo[0] += __uint_as_float(u0 << 16);
    a.lo[1] += __uint_as_float(u0 & 0xffff0000u);
    a.lo[2] += __uint_as_float(u1 << 16);
    a.lo[3] += __uint_as_float(u1 & 0xffff0000u);
    a.hi[0] += __uint_as_float(u2 << 16);
    a.hi[1] += __uint_as_float(u2 & 0xffff0000u);
    a.hi[2] += __uint_as_float(u3 << 16);
    a.hi[3] += __uint_as_float(u3 & 0xffff0000u);
    return a;
}
__device__ __forceinline__ int4 row8_pack(Row8 a) {
    int4 o;
    o.x = (int)packbf(a.lo[0], a.lo[1]);
    o.y = (int)packbf(a.lo[2], a.lo[3]);
    o.z = (int)packbf(a.hi[0], a.hi[1]);
    o.w = (int)packbf(a.hi[2], a.hi[3]);
    return o;
}

// ---------------- f32 -> bf16 bulk convert ----------------
__global__ __launch_bounds__(256) void tobf_kernel(const float* __restrict__ in,
                                                   short* __restrict__ out, int n4) {
    int i = blockIdx.x * 256 + threadIdx.x;
    if (i >= n4) return;
    float4 v = ((const float4*)in)[i];
    short4 b = { f2bf(v.x), f2bf(v.y), f2bf(v.z), f2bf(v.w) };
    ((short4*)out)[i] = b;
}

// ---------------- int counts per (relation, dst) segment: seg2 = r*N + dst ----------------
__global__ __launch_bounds__(256) void count_kernel(const int* __restrict__ dst,
                                                    const int* __restrict__ ety,
                                                    int* __restrict__ cnt, int E, int N) {
    int e = blockIdx.x * blockDim.x + threadIdx.x;
    if (e < E) atomicAdd(&cnt[ety[e] * N + dst[e]], 1);
}

// ---------------- 3-phase exclusive scan over nseg counts ----------------
#define SCAN_CHUNK 2048
#define SCAN_IT    8

__global__ __launch_bounds__(256) void scan_bsum_kernel(const int* __restrict__ cnt, int nseg,
                                                        int* __restrict__ bsum) {
    __shared__ int sd[256];
    int base = blockIdx.x * SCAN_CHUNK;
    int s = 0;
    #pragma unroll
    for (int j = 0; j < SCAN_IT; ++j) {
        int idx = base + j * 256 + threadIdx.x;
        if (idx < nseg) s += cnt[idx];
    }
    sd[threadIdx.x] = s;
    __syncthreads();
    for (int st = 128; st > 0; st >>= 1) {
        if (threadIdx.x < st) sd[threadIdx.x] += sd[threadIdx.x + st];
        __syncthreads();
    }
    if (threadIdx.x == 0) bsum[blockIdx.x] = sd[0];
}

__global__ __launch_bounds__(256) void scan_top_kernel(const int* __restrict__ bsum, int nblk,
                                                       int* __restrict__ boff,
                                                       int* __restrict__ off, int nseg) {
    if (nblk > 256) {
        if (threadIdx.x == 0) {
            int run = 0;
            for (int i = 0; i < nblk; ++i) { int t = bsum[i]; boff[i] = run; run += t; }
            off[nseg] = run;
        }
        return;
    }
    __shared__ int sd[256];
    int v = (threadIdx.x < nblk) ? bsum[threadIdx.x] : 0;
    sd[threadIdx.x] = v;
    __syncthreads();
    for (int st = 1; st < 256; st <<= 1) {
        int t = (threadIdx.x >= st) ? sd[threadIdx.x - st] : 0;
        __syncthreads();
        sd[threadIdx.x] += t;
        __syncthreads();
    }
    if (threadIdx.x < nblk) boff[threadIdx.x] = sd[threadIdx.x] - v;   // exclusive
    if (threadIdx.x == nblk - 1) off[nseg] = sd[threadIdx.x];          // total = E
}

__global__ __launch_bounds__(256) void scan_final_kernel(const int* __restrict__ cnt, int nseg,
                                                         const int* __restrict__ boff,
                                                         int* __restrict__ off,
                                                         int* __restrict__ cursor) {
    __shared__ int sd[256];
    int base = blockIdx.x * SCAN_CHUNK + threadIdx.x * SCAN_IT;
    int v[SCAN_IT];
    int s = 0;
    #pragma unroll
    for (int j = 0; j < SCAN_IT; ++j) {
        int idx = base + j;
        v[j] = (idx < nseg) ? cnt[idx] : 0;
        s += v[j];
    }
    sd[threadIdx.x] = s;
    __syncthreads();
    for (int st = 1; st < 256; st <<= 1) {
        int t = (threadIdx.x >= st) ? sd[threadIdx.x - st] : 0;
        __syncthreads();
        sd[threadIdx.x] += t;
        __syncthreads();
    }
    int run = boff[blockIdx.x] + sd[threadIdx.x] - s;   // exclusive prefix of this thread
    #pragma unroll
    for (int j = 0; j < SCAN_IT; ++j) {
        int idx = base + j;
        if (idx < nseg) { off[idx] = run; cursor[idx] = run; }
        run += v[j];
    }
}

// ---------------- bucket the source indices (CSR payload, (r,dst)-major) ----------------
__global__ __launch_bounds__(256) void reorder_kernel(const int* __restrict__ src,
                                                      const int* __restrict__ dst,
                                                      const int* __restrict__ ety,
                                                      int* __restrict__ cursor,
                                                      int* __restrict__ srt, int E, int N) {
    int e = blockIdx.x * blockDim.x + threadIdx.x;
    if (e >= E) return;
    int seg = ety[e] * N + dst[e];
    int pos = atomicAdd(&cursor[seg], 1);
    srt[pos] = src[e];
}

// ------- fused weight prep (BT1/BT2 combined rel+root, wcT) -------
#define PREP1 (R_ * DIN1 * DHID)                    // 262144
#define PREP2 (PREP1 + R_ * DHID * DOUT2)           // +131072
#define PREP3 (PREP2 + DIN1 * DHID)                 // +16384
#define PREP4 (PREP3 + DHID * DOUT2)                // +8192
#define PREP5 (PREP4 + DADR * DOUT2)                // +25600
__global__ __launch_bounds__(256) void prep_kernel(const float* __restrict__ comp1,
                                                   const float* __restrict__ basis1,
                                                   const float* __restrict__ root1,
                                                   const float* __restrict__ comp2,
                                                   const float* __restrict__ basis2,
                                                   const float* __restrict__ root2,
                                                   const float* __restrict__ wc,
                                                   short* __restrict__ BT1,
                                                   short* __restrict__ BT2,
                                                   short* __restrict__ wcT) {
    int idx = blockIdx.x * 256 + threadIdx.x;
    if (idx < PREP1) {
        int o = idx % DHID, i = (idx / DHID) % DIN1, r = idx / (DHID * DIN1);
        float acc = 0.f;
        #pragma unroll 6
        for (int b = 0; b < NBAS; ++b)
            acc += comp1[r * NBAS + b] * basis1[((size_t)b * DIN1 + i) * DHID + o];
        BT1[(size_t)o * LDB + r * DIN1 + i] = f2bf(acc);
    } else if (idx < PREP2) {
        int t = idx - PREP1;
        int o = t % DOUT2, i = (t / DOUT2) % DHID, r = t / (DOUT2 * DHID);
        float acc = 0.f;
        #pragma unroll 6
        for (int b = 0; b < NBAS; ++b)
            acc += comp2[r * NBAS + b] * basis2[((size_t)b * DHID + i) * DOUT2 + o];
        BT2[(size_t)o * LDB + r * DHID + i] = f2bf(acc);
    } else if (idx < PREP3) {
        int t = idx - PREP2;
        int o = t % DHID, i = t / DHID;
        BT1[(size_t)o * LDB + R_ * DIN1 + i] = f2bf(root1[(size_t)i * DHID + o]);
    } else if (idx < PREP4) {
        int t = idx - PREP3;
        int o = t % DOUT2, i = t / DOUT2;
        BT2[(size_t)o * LDB + R_ * DHID + i] = f2bf(root2[(size_t)i * DOUT2 + o]);
    } else if (idx < PREP5) {
        int t = idx - PREP4;
        int a = t / DOUT2, k = t % DOUT2;
        wcT[(size_t)a * DOUT2 + k] = f2bf(wc[(size_t)k * DADR + a]);
    }
}

// ------- FUSED RGCN layer (round-17 base + T14 staged gather):
//   256 thr / 4 waves, BM=32, 2 rows per 16-lane group, B in LDS.
//   Pipeline per chunk r: b1 -> issue vb(B r) -> prefetch idx r+2 ->
//   CONSUME staged feats of chunk r (VALU only, loads issued last iter) ->
//   write lA -> write lB -> ISSUE staged feat loads for chunk r+1 -> b2 ->
//   MFMA. The feat-gather latency is hidden under a full iteration. -------
template<int BN, bool OUTBF>
__global__ __launch_bounds__(256, 4)
void rgcn_fused_kernel(const short* __restrict__ featbf,   // [N][128] bf16
                       const int* __restrict__ off2,       // [R_*N+1] CSR offsets (r-major)
                       const int* __restrict__ srt,        // [E] src indices
                       const short* __restrict__ BT,       // [BN][LDB] bf16
                       const float* __restrict__ bias,
                       void* __restrict__ Hout, int N, int relu)
{
    constexpr int BM = 32, BK = 128;
    constexpr int WN = BN / 4;       // 32 (BN=128) or 16 (BN=64)
    constexpr int MR = 2;
    constexpr int NR = WN / 16;      // 2 or 1
    constexpr int BL = BN / 16;      // B int4-loads per thread (8 or 4)

    __shared__ short lA[BM * BK];
    __shared__ short lB[BN * BK];

    const int tid  = threadIdx.x;
    const int lane = tid & 63;
    const int wv   = tid >> 6;       // wave = column group
    const int g16  = tid >> 4;       // 16 groups of 16 lanes
    const int l16  = tid & 15;       // int4 slot within 128-bf16 row
    const int n0   = blockIdx.x * BM;
    const int row0 = n0 + g16;
    const int row1 = n0 + 16 + g16;

    f32x4 acc[MR][NR];
    #pragma unroll
    for (int m = 0; m < MR; ++m)
        #pragma unroll
        for (int n = 0; n < NR; ++n)
            acc[m][n] = (f32x4){0.f, 0.f, 0.f, 0.f};

    // ---- lane r holds segment bounds of relation r for both rows ----
    int b0v = 0, e0v = 0, b1v = 0, e1v = 0;
    if (row0 < N) { b0v = off2[l16 * N + row0]; e0v = off2[l16 * N + row0 + 1]; }
    if (row1 < N) { b1v = off2[l16 * N + row1]; e1v = off2[l16 * N + row1 + 1]; }

    // ---- chunk 0 state + staged feats (exposed once) ----
    int cb0 = __shfl(b0v, 0, 16), cc0 = __shfl(e0v, 0, 16) - cb0;
    int cb1 = __shfl(b1v, 0, 16), cc1 = __shfl(e1v, 0, 16) - cb1;
    int cidx0 = (l16 < (cc0 < 16 ? cc0 : 16)) ? srt[cb0 + l16] : 0;
    int cidx1 = (l16 < (cc1 < 16 ? cc1 : 16)) ? srt[cb1 + l16] : 0;

    int4 sc0[4], sc1[4], sn0[4], sn1[4];
    #pragma unroll
    for (int j = 0; j < 4; ++j) {
        int i0 = __shfl(cidx0, j, 16);
        sc0[j] = (j < cc0) ? *(const int4*)(featbf + (size_t)i0 * KCH + l16 * 8)
                           : (int4){0, 0, 0, 0};
        int i1 = __shfl(cidx1, j, 16);
        sc1[j] = (j < cc1) ? *(const int4*)(featbf + (size_t)i1 * KCH + l16 * 8)
                           : (int4){0, 0, 0, 0};
    }

    // ---- chunk 1 bounds + index prefetch ----
    int nb0 = __shfl(b0v, 1, 16), nc0 = __shfl(e0v, 1, 16) - nb0;
    int nb1 = __shfl(b1v, 1, 16), nc1 = __shfl(e1v, 1, 16) - nb1;
    int nidx0 = (l16 < (nc0 < 16 ? nc0 : 16)) ? srt[nb0 + l16] : 0;
    int nidx1 = (l16 < (nc1 < 16 ? nc1 : 16)) ? srt[nb1 + l16] : 0;

    for (int r = 0; r <= R_; ++r) {
        __syncthreads();              // b1: previous MFMA done; lA/lB free

        // ---- 1. issue B loads for chunk r (vb short-lived) ----
        int4 vb[BL];
        #pragma unroll
        for (int j = 0; j < BL; ++j)
            vb[j] = *(const int4*)(BT + (size_t)(j * 16 + g16) * LDB + r * BK + l16 * 8);

        // ---- 2. prefetch bounds + indices for chunk r+2 ----
        int pb0 = 0, pc0 = 0, pidx0 = 0, pb1 = 0, pc1 = 0, pidx1 = 0;
        {
            int rr = r + 2;
            if (rr < R_) {
                pb0 = __shfl(b0v, rr, 16); pc0 = __shfl(e0v, rr, 16) - pb0;
                pb1 = __shfl(b1v, rr, 16); pc1 = __shfl(e1v, rr, 16) - pb1;
                pidx0 = (l16 < (pc0 < 16 ? pc0 : 16)) ? srt[pb0 + l16] : 0;
                pidx1 = (l16 < (pc1 < 16 ? pc1 : 16)) ? srt[pb1 + l16] : 0;
            } else if (rr == R_) {       // root chunk: c=1, idx=row
                pc0 = (row0 < N) ? 1 : 0; pidx0 = (row0 < N) ? row0 : 0;
                pc1 = (row1 < N) ? 1 : 0; pidx1 = (row1 < N) ? row1 : 0;
            }
        }

        // ---- 3. consume staged chunk r (VALU only; rare overflow loads) ----
        Row8 a0 = row8_zero(), a1 = row8_zero();
        #pragma unroll
        for (int j = 0; j < 4; ++j) {
            if (j < cc0) a0 = row8_add(a0, sc0[j]);
            if (j < cc1) a1 = row8_add(a1, sc1[j]);
        }
        if (cc0 > 4) {
            for (int j = 4; j < cc0 && j < 16; ++j) {
                int i0 = __shfl(cidx0, j, 16);
                a0 = row8_add(a0, *(const int4*)(featbf + (size_t)i0 * KCH + l16 * 8));
            }
            for (int p = cb0 + 16; p < cb0 + cc0; ++p)
                a0 = row8_add(a0, *(const int4*)(featbf + (size_t)srt[p] * KCH + l16 * 8));
        }
        if (cc1 > 4) {
            for (int j = 4; j < cc1 && j < 16; ++j) {
                int i1 = __shfl(cidx1, j, 16);
                a1 = row8_add(a1, *(const int4*)(featbf + (size_t)i1 * KCH + l16 * 8));
            }
            for (int p = cb1 + 16; p < cb1 + cc1; ++p)
                a1 = row8_add(a1, *(const int4*)(featbf + (size_t)srt[p] * KCH + l16 * 8));
        }
        {
            float s0 = 1.f / (float)(cc0 > 1 ? cc0 : 1);
            a0.lo *= s0; a0.hi *= s0;
            float s1 = 1.f / (float)(cc1 > 1 ? cc1 : 1);
            a1.lo *= s1; a1.hi *= s1;
        }

        // ---- 4. write A rows, then B tile (vb dies here) ----
        {
            int byte0 = ((g16 * BK + l16 * 8) << 1) ^ ((g16 & 15) << 4);
            *(int4*)((char*)lA + byte0) = row8_pack(a0);
            int rowl = 16 + g16;
            int byte1 = ((rowl * BK + l16 * 8) << 1) ^ ((rowl & 15) << 4);
            *(int4*)((char*)lA + byte1) = row8_pack(a1);
        }
        #pragma unroll
        for (int j = 0; j < BL; ++j) {
            int o = j * 16 + g16;
            int byte = ((o * BK + l16 * 8) << 1) ^ ((o & 15) << 4);
            *(int4*)((char*)lB + byte) = vb[j];
        }

        // ---- 5. issue staged feat loads for chunk r+1 ----
        if (r < R_) {
            #pragma unroll
            for (int j = 0; j < 4; ++j) {
                int i0 = __shfl(nidx0, j, 16);
                sn0[j] = (j < nc0) ? *(const int4*)(featbf + (size_t)i0 * KCH + l16 * 8)
                                   : (int4){0, 0, 0, 0};
                int i1 = __shfl(nidx1, j, 16);
                sn1[j] = (j < nc1) ? *(const int4*)(featbf + (size_t)i1 * KCH + l16 * 8)
                                   : (int4){0, 0, 0, 0};
            }
        }
        __syncthreads();              // b2: lA + lB published

        // ---- 6. MFMA chunk r ----
        #pragma unroll
        for (int kk = 0; kk < BK / 32; ++kk) {
            const int kpos = kk * 32 + (lane >> 4) * 8;
            bf16x8 af[MR], bfr[NR];
            #pragma unroll
            for (int m = 0; m < MR; ++m) {
                int row = m * 16 + (lane & 15);
                af[m] = *(const bf16x8*)((const char*)lA +
                         (((row * BK + kpos) << 1) ^ ((row & 15) << 4)));
            }
            #pragma unroll
            for (int n = 0; n < NR; ++n) {
                int col = wv * WN + n * 16 + (lane & 15);
                bfr[n] = *(const bf16x8*)((const char*)lB +
                         (((col * BK + kpos) << 1) ^ ((col & 15) << 4)));
            }
            #pragma unroll
            for (int m = 0; m < MR; ++m)
                #pragma unroll
                for (int n = 0; n < NR; ++n)
                    acc[m][n] = __builtin_amdgcn_mfma_f32_16x16x32_bf16(
                        af[m], bfr[n], acc[m][n], 0, 0, 0);
        }

        // ---- 7. rotate pipeline state ----
        cb0 = nb0; cc0 = nc0; cidx0 = nidx0;
        cb1 = nb1; cc1 = nc1; cidx1 = nidx1;
        nb0 = pb0; nc0 = pc0; nidx0 = pidx0;
        nb1 = pb1; nc1 = pc1; nidx1 = pidx1;
        #pragma unroll
        for (int j = 0; j < 4; ++j) { sc0[j] = sn0[j]; sc1[j] = sn1[j]; }
    }

    // ---- epilogue: C/D layout row=(lane>>4)*4+i, col=lane&15 ----
    #pragma unroll
    for (int m = 0; m < MR; ++m)
        #pragma unroll
        for (int n = 0; n < NR; ++n)
            #pragma unroll
            for (int i = 0; i < 4; ++i) {
                int row  = m * 16 + ((lane >> 4) << 2) + i;
                int col  = wv * WN + n * 16 + (lane & 15);
                int grow = n0 + row;
                if (grow >= N) continue;
                float v = acc[m][n][i] + bias[col];
                if (relu) v = fmaxf(v, 0.f);
                if (OUTBF) ((short*)Hout)[(size_t)grow * BN + col] = f2bf(v);
                else       ((float*)Hout)[(size_t)grow * BN + col] = v;
            }
}

// ------- classifier MFMA GEMM: out[n][a] = h2[n][:] @ wcT[a][:] + bc[a] -------
__global__ __launch_bounds__(256)
void classifier_gemm_kernel(const short* __restrict__ h2bf,   // [N][64] bf16
                            const short* __restrict__ wcT,    // [400][64] bf16
                            const float* __restrict__ bc,
                            float* __restrict__ out, int N)
{
    constexpr int BM = 128, BN = 80, BK = 64;
    constexpr int MR = 2, NR = 5;

    __shared__ short lA[BM * BK];
    __shared__ short lB[BN * BK];

    const int tid  = threadIdx.x;
    const int lane = tid & 63;
    const int wv   = tid >> 6;             // wave = row group (32 rows each)
    const int nodeBase = blockIdx.x * BM;
    const int colBase  = blockIdx.y * BN;

    const int t8  = tid & 7;     // 16B unit within 64-bf16 row (8 units)
    const int r32 = tid >> 3;    // 32 rows per pass

    #pragma unroll
    for (int it = 0; it < 4; ++it) {
        int row  = it * 32 + r32;
        int grow = nodeBase + row;
        int4 v = {0, 0, 0, 0};
        if (grow < N) v = *(const int4*)(h2bf + (size_t)grow * DOUT2 + t8 * 8);
        int byte = ((row * BK + t8 * 8) << 1) ^ ((row & 7) << 4);
        *(int4*)((char*)lA + byte) = v;
    }
    for (int o = r32; o < BN; o += 32) {
        int4 v = *(const int4*)(wcT + (size_t)(colBase + o) * DOUT2 + t8 * 8);
        int byte = ((o * BK + t8 * 8) << 1) ^ ((o & 7) << 4);
        *(int4*)((char*)lB + byte) = v;
    }
    __syncthreads();

    f32x4 acc[MR][NR];
    #pragma unroll
    for (int m = 0; m < MR; ++m)
        #pragma unroll
        for (int n = 0; n < NR; ++n)
            acc[m][n] = (f32x4){0.f, 0.f, 0.f, 0.f};

    #pragma unroll
    for (int kk = 0; kk < BK / 32; ++kk) {
        const int kpos = kk * 32 + (lane >> 4) * 8;
        bf16x8 af[MR], bfr[NR];
        #pragma unroll
        for (int m = 0; m < MR; ++m) {
            int row = wv * 32 + m * 16 + (lane & 15);
            af[m] = *(const bf16x8*)((const char*)lA +
                     (((row * BK + kpos) << 1) ^ ((row & 7) << 4)));
        }
        #pragma unroll
        for (int n = 0; n < NR; ++n) {
            int col = n * 16 + (lane & 15);
            bfr[n] = *(const bf16x8*)((const char*)lB +
                     (((col * BK + kpos) << 1) ^ ((col & 7) << 4)));
        }
        #pragma unroll
        for (int m = 0; m < MR; ++m)
            #pragma unroll
            for (int n = 0; n < NR; ++n)
                acc[m][n] = __builtin_amdgcn_mfma_f32_16x16x32_bf16(
                    af[m], bfr[n], acc[m][n], 0, 0, 0);
    }

    #pragma unroll
    for (int m = 0; m < MR; ++m)
        #pragma unroll
        for (int n = 0; n < NR; ++n)
            #pragma unroll
            for (int i = 0; i < 4; ++i) {
                int row  = wv * 32 + m * 16 + ((lane >> 4) << 2) + i;
                int col  = n * 16 + (lane & 15);
                int grow = nodeBase + row;
                if (grow >= N) continue;
                int gcol = colBase + col;
                out[(size_t)grow * DADR + gcol] = acc[m][n][i] + bc[gcol];
            }
}

static inline size_t align16(size_t x) { return (x + 15) & ~(size_t)15; }

extern "C" void kernel_launch(void* const* d_in, const int* in_sizes, int n_in,
                              void* d_out, int out_size, void* d_ws, size_t ws_size,
                              hipStream_t stream) {
    const float* x      = (const float*)d_in[0];
    const int*   ei     = (const int*)d_in[1];
    const int*   et     = (const int*)d_in[2];
    const float* comp1  = (const float*)d_in[3];
    const float* basis1 = (const float*)d_in[4];
    const float* root1  = (const float*)d_in[5];
    const float* bias1  = (const float*)d_in[6];
    const float* comp2  = (const float*)d_in[7];
    const float* basis2 = (const float*)d_in[8];
    const float* root2  = (const float*)d_in[9];
    const float* bias2  = (const float*)d_in[10];
    const float* wc     = (const float*)d_in[11];
    const float* bc     = (const float*)d_in[12];
    float* out = (float*)d_out;

    const int E = in_sizes[1] / 2;
    const int N = in_sizes[0] / DIN1;
    const int* srcp = ei;
    const int* dstp = ei + E;

    const int NSEG = N * R_;
    const int NBLK = (NSEG + SCAN_CHUNK - 1) / SCAN_CHUNK;

    char* ws = (char*)d_ws;
    size_t o = 0;
    int*   cntI   = (int*)(ws + o);   o = align16(o + (size_t)NSEG * 4);
    int*   off2   = (int*)(ws + o);   o = align16(o + (size_t)(NSEG + 1) * 4);
    int*   cursor = (int*)(ws + o);   o = align16(o + (size_t)NSEG * 4);
    int*   bsum   = (int*)(ws + o);   o = align16(o + (size_t)NBLK * 4);
    int*   boff   = (int*)(ws + o);   o = align16(o + (size_t)NBLK * 4);
    int*   srt    = (int*)(ws + o);   o = align16(o + (size_t)E * 4);
    short* BT1    = (short*)(ws + o); o = align16(o + (size_t)DHID * LDB * 2);
    short* BT2    = (short*)(ws + o); o = align16(o + (size_t)DOUT2 * LDB * 2);
    short* wcTb   = (short*)(ws + o); o = align16(o + (size_t)DADR * DOUT2 * 2);
    short* xbf    = (short*)(ws + o); o = align16(o + (size_t)N * DIN1 * 2);
    short* h1bf   = (short*)(ws + o); o = align16(o + (size_t)N * DHID * 2);
    short* h2bf   = (short*)(ws + o); o = align16(o + (size_t)N * DOUT2 * 2);

    // ---- bf16 copy of x ----
    const int n4 = N * DIN1 / 4;
    tobf_kernel<<<(n4 + 255) / 256, 256, 0, stream>>>(x, xbf, n4);

    // ---- CSR build, (relation, dst)-major ----
    hipMemsetAsync(cntI, 0, (size_t)NSEG * 4, stream);
    count_kernel<<<(E + 255) / 256, 256, 0, stream>>>(dstp, et, cntI, E, N);
    scan_bsum_kernel<<<NBLK, 256, 0, stream>>>(cntI, NSEG, bsum);
    scan_top_kernel<<<1, 256, 0, stream>>>(bsum, NBLK, boff, off2, NSEG);
    scan_final_kernel<<<NBLK, 256, 0, stream>>>(cntI, NSEG, boff, off2, cursor);
    reorder_kernel<<<(E + 255) / 256, 256, 0, stream>>>(srcp, dstp, et, cursor, srt, E, N);

    // ---- weights (fused prep) ----
    prep_kernel<<<(PREP5 + 255) / 256, 256, 0, stream>>>(comp1, basis1, root1,
                                                         comp2, basis2, root2, wc,
                                                         BT1, BT2, wcTb);

    // ---- two fused RGCN layers ----
    const int gGrid = (N + 31) / 32;
    rgcn_fused_kernel<DHID, true><<<gGrid, 256, 0, stream>>>(xbf,  off2, srt, BT1, bias1, h1bf, N, 1);
    rgcn_fused_kernel<DOUT2, true><<<gGrid, 256, 0, stream>>>(h1bf, off2, srt, BT2, bias2, h2bf, N, 0);

    // ---- classifier (MFMA) ----
    dim3 cGrid((N + 127) / 128, DADR / 80);
    classifier_gemm_kernel<<<cGrid, 256, 0, stream>>>(h2bf, wcTb, bc, out, N);
}

// Round 19
// 295.079 us; speedup vs baseline: 1.0461x; 1.0461x over previous
//
#include <hip/hip_runtime.h>

#define R_    16
#define NBAS  30
#define DIN1  128
#define DHID  128
#define DOUT2 64
#define DADR  400
#define KCH   128              // feature width of both layer inputs

typedef __attribute__((ext_vector_type(8))) short bf16x8;
typedef __attribute__((ext_vector_type(4))) float f32x4;

__device__ __forceinline__ short f2bf(float f) {
    unsigned u = __float_as_uint(f);
    u += 0x7fffu + ((u >> 16) & 1u);   // round-to-nearest-even
    return (short)(u >> 16);
}
__device__ __forceinline__ unsigned packbf(float lo, float hi) {
    return (unsigned)(unsigned short)f2bf(lo) | ((unsigned)(unsigned short)f2bf(hi) << 16);
}

struct Row8 { f32x4 lo, hi; };

__device__ __forceinline__ Row8 row8_zero() {
    Row8 z; z.lo = (f32x4){0.f,0.f,0.f,0.f}; z.hi = (f32x4){0.f,0.f,0.f,0.f}; return z;
}
__device__ __forceinline__ Row8 row8_add(Row8 a, int4 v) {
    unsigned u0 = (unsigned)v.x, u1 = (unsigned)v.y, u2 = (unsigned)v.z, u3 = (unsigned)v.w;
    a.lo[0] += __uint_as_float(u0 << 16);
    a.lo[1] += __uint_as_float(u0 & 0xffff0000u);
    a.lo[2] += __uint_as_float(u1 << 16);
    a.lo[3] += __uint_as_float(u1 & 0xffff0000u);
    a.hi[0] += __uint_as_float(u2 << 16);
    a.hi[1] += __uint_as_float(u2 & 0xffff0000u);
    a.hi[2] += __uint_as_float(u3 << 16);
    a.hi[3] += __uint_as_float(u3 & 0xffff0000u);
    return a;
}
__device__ __forceinline__ int4 row8_pack(Row8 a) {
    int4 o;
    o.x = (int)packbf(a.lo[0], a.lo[1]);
    o.y = (int)packbf(a.lo[2], a.lo[3]);
    o.z = (int)packbf(a.hi[0], a.hi[1]);
    o.w = (int)packbf(a.hi[2], a.hi[3]);
    return o;
}

// async 16B global -> LDS copy (dest = lds_uniform + lane*16)
__device__ __forceinline__ void gload_lds16(const void* g, void* l) {
    __builtin_amdgcn_global_load_lds(
        (const __attribute__((address_space(1))) unsigned int*)g,
        (__attribute__((address_space(3))) unsigned int*)l, 16, 0, 0);
}

// swizzled-image short index for B element (chunk r, out-col o, in-ch k)
__device__ __forceinline__ size_t swzidx(int r, int o, int k, int chStride) {
    int ib = ((o * 256 + ((k >> 3) << 4)) ^ ((o & 15) << 4)) + ((k & 7) << 1);
    return (size_t)r * chStride + (ib >> 1);
}

// gather-mean using PRELOADED indices (idx = srt[b+l16], broadcast via shfl).
__device__ __forceinline__ Row8 gather_idx(const short* __restrict__ featbf,
                                           const int* __restrict__ srt,
                                           int b, int c, int idx, int l16) {
    Row8 a = row8_zero();
    int s = c < 16 ? c : 16;
    int j = 0;
    for (; j + 4 <= s; j += 4) {
        int i0 = __shfl(idx, j, 16);
        int i1 = __shfl(idx, j + 1, 16);
        int i2 = __shfl(idx, j + 2, 16);
        int i3 = __shfl(idx, j + 3, 16);
        int4 v0 = *(const int4*)(featbf + (size_t)i0 * KCH + l16 * 8);
        int4 v1 = *(const int4*)(featbf + (size_t)i1 * KCH + l16 * 8);
        int4 v2 = *(const int4*)(featbf + (size_t)i2 * KCH + l16 * 8);
        int4 v3 = *(const int4*)(featbf + (size_t)i3 * KCH + l16 * 8);
        a = row8_add(a, v0); a = row8_add(a, v1);
        a = row8_add(a, v2); a = row8_add(a, v3);
    }
    for (; j + 2 <= s; j += 2) {
        int i0 = __shfl(idx, j, 16);
        int i1 = __shfl(idx, j + 1, 16);
        int4 v0 = *(const int4*)(featbf + (size_t)i0 * KCH + l16 * 8);
        int4 v1 = *(const int4*)(featbf + (size_t)i1 * KCH + l16 * 8);
        a = row8_add(a, v0); a = row8_add(a, v1);
    }
    if (j < s) {
        int i0 = __shfl(idx, j, 16);
        a = row8_add(a, *(const int4*)(featbf + (size_t)i0 * KCH + l16 * 8));
    }
    for (int p = b + 16; p < b + c; ++p)   // rare tail (>16 edges)
        a = row8_add(a, *(const int4*)(featbf + (size_t)srt[p] * KCH + l16 * 8));
    float sc = 1.f / (float)(c > 1 ? c : 1);
    a.lo *= sc; a.hi *= sc;
    return a;
}

// ------- fused setup: tobf (x->bf16) + edge counts + weight prep (swizzled images + wcT) -------
#define PREP1 (R_ * DIN1 * DHID)                    // 262144
#define PREP2 (PREP1 + R_ * DHID * DOUT2)           // +131072
#define PREP3 (PREP2 + DIN1 * DHID)                 // +16384
#define PREP4 (PREP3 + DHID * DOUT2)                // +8192
#define PREP5 (PREP4 + DADR * DOUT2)                // +25600
__global__ __launch_bounds__(256)
void setup_kernel(const float* __restrict__ x, short* __restrict__ xbf, int n4,
                  const int* __restrict__ dst, const int* __restrict__ ety,
                  int* __restrict__ cnt, int E, int N,
                  const float* __restrict__ comp1, const float* __restrict__ basis1,
                  const float* __restrict__ root1,
                  const float* __restrict__ comp2, const float* __restrict__ basis2,
                  const float* __restrict__ root2,
                  const float* __restrict__ wc,
                  short* __restrict__ BT1, short* __restrict__ BT2,
                  short* __restrict__ wcT) {
    int gid = blockIdx.x * 256 + threadIdx.x;
    if (gid < n4) {
        float4 v = ((const float4*)x)[gid];
        short4 b = { f2bf(v.x), f2bf(v.y), f2bf(v.z), f2bf(v.w) };
        ((short4*)xbf)[gid] = b;
        return;
    }
    gid -= n4;
    if (gid < E) {
        atomicAdd(&cnt[ety[gid] * N + dst[gid]], 1);
        return;
    }
    int idx = gid - E;
    if (idx < PREP1) {
        int o = idx % DHID, i = (idx / DHID) % DIN1, r = idx / (DHID * DIN1);
        float acc = 0.f;
        #pragma unroll 6
        for (int b = 0; b < NBAS; ++b)
            acc += comp1[r * NBAS + b] * basis1[((size_t)b * DIN1 + i) * DHID + o];
        BT1[swzidx(r, o, i, DHID * 128)] = f2bf(acc);
    } else if (idx < PREP2) {
        int t = idx - PREP1;
        int o = t % DOUT2, i = (t / DOUT2) % DHID, r = t / (DOUT2 * DHID);
        float acc = 0.f;
        #pragma unroll 6
        for (int b = 0; b < NBAS; ++b)
            acc += comp2[r * NBAS + b] * basis2[((size_t)b * DHID + i) * DOUT2 + o];
        BT2[swzidx(r, o, i, DOUT2 * 128)] = f2bf(acc);
    } else if (idx < PREP3) {
        int t = idx - PREP2;
        int o = t % DHID, i = t / DHID;
        BT1[swzidx(R_, o, i, DHID * 128)] = f2bf(root1[(size_t)i * DHID + o]);
    } else if (idx < PREP4) {
        int t = idx - PREP3;
        int o = t % DOUT2, i = t / DOUT2;
        BT2[swzidx(R_, o, i, DOUT2 * 128)] = f2bf(root2[(size_t)i * DOUT2 + o]);
    } else if (idx < PREP5) {
        int t = idx - PREP4;
        int a = t / DOUT2, k = t % DOUT2;
        wcT[(size_t)a * DOUT2 + k] = f2bf(wc[(size_t)k * DADR + a]);
    }
}

// ---------------- 3-phase exclusive scan over nseg counts ----------------
#define SCAN_CHUNK 2048
#define SCAN_IT    8

__global__ __launch_bounds__(256) void scan_bsum_kernel(const int* __restrict__ cnt, int nseg,
                                                        int* __restrict__ bsum) {
    __shared__ int sd[256];
    int base = blockIdx.x * SCAN_CHUNK;
    int s = 0;
    #pragma unroll
    for (int j = 0; j < SCAN_IT; ++j) {
        int idx = base + j * 256 + threadIdx.x;
        if (idx < nseg) s += cnt[idx];
    }
    sd[threadIdx.x] = s;
    __syncthreads();
    for (int st = 128; st > 0; st >>= 1) {
        if (threadIdx.x < st) sd[threadIdx.x] += sd[threadIdx.x + st];
        __syncthreads();
    }
    if (threadIdx.x == 0) bsum[blockIdx.x] = sd[0];
}

__global__ __launch_bounds__(256) void scan_top_kernel(const int* __restrict__ bsum, int nblk,
                                                       int* __restrict__ boff,
                                                       int* __restrict__ off, int nseg) {
    if (nblk > 256) {
        if (threadIdx.x == 0) {
            int run = 0;
            for (int i = 0; i < nblk; ++i) { int t = bsum[i]; boff[i] = run; run += t; }
            off[nseg] = run;
        }
        return;
    }
    __shared__ int sd[256];
    int v = (threadIdx.x < nblk) ? bsum[threadIdx.x] : 0;
    sd[threadIdx.x] = v;
    __syncthreads();
    for (int st = 1; st < 256; st <<= 1) {
        int t = (threadIdx.x >= st) ? sd[threadIdx.x - st] : 0;
        __syncthreads();
        sd[threadIdx.x] += t;
        __syncthreads();
    }
    if (threadIdx.x < nblk) boff[threadIdx.x] = sd[threadIdx.x] - v;   // exclusive
    if (threadIdx.x == nblk - 1) off[nseg] = sd[threadIdx.x];          // total = E
}

__global__ __launch_bounds__(256) void scan_final_kernel(const int* __restrict__ cnt, int nseg,
                                                         const int* __restrict__ boff,
                                                         int* __restrict__ off,
                                                         int* __restrict__ cursor) {
    __shared__ int sd[256];
    int base = blockIdx.x * SCAN_CHUNK + threadIdx.x * SCAN_IT;
    int v[SCAN_IT];
    int s = 0;
    #pragma unroll
    for (int j = 0; j < SCAN_IT; ++j) {
        int idx = base + j;
        v[j] = (idx < nseg) ? cnt[idx] : 0;
        s += v[j];
    }
    sd[threadIdx.x] = s;
    __syncthreads();
    for (int st = 1; st < 256; st <<= 1) {
        int t = (threadIdx.x >= st) ? sd[threadIdx.x - st] : 0;
        __syncthreads();
        sd[threadIdx.x] += t;
        __syncthreads();
    }
    int run = boff[blockIdx.x] + sd[threadIdx.x] - s;
    #pragma unroll
    for (int j = 0; j < SCAN_IT; ++j) {
        int idx = base + j;
        if (idx < nseg) { off[idx] = run; cursor[idx] = run; }
        run += v[j];
    }
}

// ---------------- bucket the source indices (CSR payload, (r,dst)-major) ----------------
__global__ __launch_bounds__(256) void reorder_kernel(const int* __restrict__ src,
                                                      const int* __restrict__ dst,
                                                      const int* __restrict__ ety,
                                                      int* __restrict__ cursor,
                                                      int* __restrict__ srt, int E, int N) {
    int e = blockIdx.x * blockDim.x + threadIdx.x;
    if (e >= E) return;
    int seg = ety[e] * N + dst[e];
    int pos = atomicAdd(&cursor[seg], 1);
    srt[pos] = src[e];
}

// ------- FUSED RGCN layer (round-17 pipeline, B staged via global_load_lds):
//   256 thr / 4 waves, BM=32, 2 rows per 16-lane group. Per chunk r:
//   b1 -> issue async B stage (no VGPRs) -> prefetch idx r+1 -> gather r ->
//   write lA -> b2 (drains vmcnt: B landed) -> MFMA. B source is a
//   pre-swizzled per-chunk image so the linear async copy reproduces the
//   swizzled LDS layout. -------
template<int BN, bool OUTBF>
__global__ __launch_bounds__(256, 4)
void rgcn_fused_kernel(const short* __restrict__ featbf,   // [N][128] bf16
                       const int* __restrict__ off2,       // [R_*N+1] CSR offsets (r-major)
                       const int* __restrict__ srt,        // [E] src indices
                       const short* __restrict__ BT,       // swizzled chunk images
                       const float* __restrict__ bias,
                       void* __restrict__ Hout, int N, int relu)
{
    constexpr int BM = 32, BK = 128;
    constexpr int WN = BN / 4;       // 32 (BN=128) or 16 (BN=64)
    constexpr int MR = 2;
    constexpr int NR = WN / 16;      // 2 or 1
    constexpr int NCOPY = BN / 16;   // async 4KB copies per chunk (8 or 4)

    __shared__ short lA[BM * BK];
    __shared__ short lB[BN * BK];

    const int tid  = threadIdx.x;
    const int lane = tid & 63;
    const int wv   = tid >> 6;       // wave = column group
    const int g16  = tid >> 4;       // 16 groups of 16 lanes
    const int l16  = tid & 15;       // int4 slot within 128-bf16 row
    const int n0   = blockIdx.x * BM;
    const int row0 = n0 + g16;
    const int row1 = n0 + 16 + g16;

    f32x4 acc[MR][NR];
    #pragma unroll
    for (int m = 0; m < MR; ++m)
        #pragma unroll
        for (int n = 0; n < NR; ++n)
            acc[m][n] = (f32x4){0.f, 0.f, 0.f, 0.f};

    // ---- lane r holds segment bounds of relation r for both rows ----
    int b0v = 0, e0v = 0, b1v = 0, e1v = 0;
    if (row0 < N) { b0v = off2[l16 * N + row0]; e0v = off2[l16 * N + row0 + 1]; }
    if (row1 < N) { b1v = off2[l16 * N + row1]; e1v = off2[l16 * N + row1 + 1]; }

    // current chunk (0) bounds + index vectors
    int cb0 = __shfl(b0v, 0, 16), cc0 = __shfl(e0v, 0, 16) - cb0;
    int cb1 = __shfl(b1v, 0, 16), cc1 = __shfl(e1v, 0, 16) - cb1;
    int cidx0 = (l16 < (cc0 < 16 ? cc0 : 16)) ? srt[cb0 + l16] : 0;
    int cidx1 = (l16 < (cc1 < 16 ? cc1 : 16)) ? srt[cb1 + l16] : 0;

    for (int r = 0; r <= R_; ++r) {
        __syncthreads();              // b1: previous MFMA reads done; lA/lB free

        // ---- 1. async-stage B chunk r into lB (zero VGPR cost) ----
        {
            const char* srcB = (const char*)BT + (size_t)r * BN * 256;
            #pragma unroll
            for (int j = 0; j < NCOPY; ++j) {
                const char* g = srcB + j * 4096 + wv * 1024 + (lane << 4);
                char* l = (char*)lB + j * 4096 + wv * 1024;
                gload_lds16(g, l);
            }
        }

        // ---- 2. prefetch next chunk's bounds + srt indices ----
        int nb0 = 0, nc0 = 0, nb1 = 0, nc1 = 0, nidx0 = 0, nidx1 = 0;
        if (r + 1 < R_) {
            nb0 = __shfl(b0v, r + 1, 16); nc0 = __shfl(e0v, r + 1, 16) - nb0;
            nb1 = __shfl(b1v, r + 1, 16); nc1 = __shfl(e1v, r + 1, 16) - nb1;
            nidx0 = (l16 < (nc0 < 16 ? nc0 : 16)) ? srt[nb0 + l16] : 0;
            nidx1 = (l16 < (nc1 < 16 ? nc1 : 16)) ? srt[nb1 + l16] : 0;
        }

        // ---- 3. gather chunk r (only feat loads on the chain) ----
        Row8 a0, a1;
        if (r < R_) {
            a0 = gather_idx(featbf, srt, cb0, cc0, cidx0, l16);
            a1 = gather_idx(featbf, srt, cb1, cc1, cidx1, l16);
        } else {
            a0 = row8_zero(); a1 = row8_zero();
            if (row0 < N)
                a0 = row8_add(a0, *(const int4*)(featbf + (size_t)row0 * KCH + l16 * 8));
            if (row1 < N)
                a1 = row8_add(a1, *(const int4*)(featbf + (size_t)row1 * KCH + l16 * 8));
        }

        // ---- 4. write A rows to LDS ----
        {
            int byte0 = ((g16 * BK + l16 * 8) << 1) ^ ((g16 & 15) << 4);
            *(int4*)((char*)lA + byte0) = row8_pack(a0);
            int rowl = 16 + g16;
            int byte1 = ((rowl * BK + l16 * 8) << 1) ^ ((rowl & 15) << 4);
            *(int4*)((char*)lA + byte1) = row8_pack(a1);
        }
        __syncthreads();              // b2: lA published, async B landed (vmcnt drain)

        // ---- 5. MFMA chunk r ----
        #pragma unroll
        for (int kk = 0; kk < BK / 32; ++kk) {
            const int kpos = kk * 32 + (lane >> 4) * 8;
            bf16x8 af[MR], bfr[NR];
            #pragma unroll
            for (int m = 0; m < MR; ++m) {
                int row = m * 16 + (lane & 15);
                af[m] = *(const bf16x8*)((const char*)lA +
                         (((row * BK + kpos) << 1) ^ ((row & 15) << 4)));
            }
            #pragma unroll
            for (int n = 0; n < NR; ++n) {
                int col = wv * WN + n * 16 + (lane & 15);
                bfr[n] = *(const bf16x8*)((const char*)lB +
                         (((col * BK + kpos) << 1) ^ ((col & 15) << 4)));
            }
            #pragma unroll
            for (int m = 0; m < MR; ++m)
                #pragma unroll
                for (int n = 0; n < NR; ++n)
                    acc[m][n] = __builtin_amdgcn_mfma_f32_16x16x32_bf16(
                        af[m], bfr[n], acc[m][n], 0, 0, 0);
        }

        // ---- 6. rotate prefetched index state ----
        cb0 = nb0; cc0 = nc0; cidx0 = nidx0;
        cb1 = nb1; cc1 = nc1; cidx1 = nidx1;
    }

    // ---- epilogue: C/D layout row=(lane>>4)*4+i, col=lane&15 ----
    #pragma unroll
    for (int m = 0; m < MR; ++m)
        #pragma unroll
        for (int n = 0; n < NR; ++n)
            #pragma unroll
            for (int i = 0; i < 4; ++i) {
                int row  = m * 16 + ((lane >> 4) << 2) + i;
                int col  = wv * WN + n * 16 + (lane & 15);
                int grow = n0 + row;
                if (grow >= N) continue;
                float v = acc[m][n][i] + bias[col];
                if (relu) v = fmaxf(v, 0.f);
                if (OUTBF) ((short*)Hout)[(size_t)grow * BN + col] = f2bf(v);
                else       ((float*)Hout)[(size_t)grow * BN + col] = v;
            }
}

// ------- classifier MFMA GEMM: out[n][a] = h2[n][:] @ wcT[a][:] + bc[a] -------
__global__ __launch_bounds__(256)
void classifier_gemm_kernel(const short* __restrict__ h2bf,   // [N][64] bf16
                            const short* __restrict__ wcT,    // [400][64] bf16
                            const float* __restrict__ bc,
                            float* __restrict__ out, int N)
{
    constexpr int BM = 128, BN = 80, BK = 64;
    constexpr int MR = 2, NR = 5;

    __shared__ short lA[BM * BK];
    __shared__ short lB[BN * BK];

    const int tid  = threadIdx.x;
    const int lane = tid & 63;
    const int wv   = tid >> 6;
    const int nodeBase = blockIdx.x * BM;
    const int colBase  = blockIdx.y * BN;

    const int t8  = tid & 7;
    const int r32 = tid >> 3;

    #pragma unroll
    for (int it = 0; it < 4; ++it) {
        int row  = it * 32 + r32;
        int grow = nodeBase + row;
        int4 v = {0, 0, 0, 0};
        if (grow < N) v = *(const int4*)(h2bf + (size_t)grow * DOUT2 + t8 * 8);
        int byte = ((row * BK + t8 * 8) << 1) ^ ((row & 7) << 4);
        *(int4*)((char*)lA + byte) = v;
    }
    for (int o = r32; o < BN; o += 32) {
        int4 v = *(const int4*)(wcT + (size_t)(colBase + o) * DOUT2 + t8 * 8);
        int byte = ((o * BK + t8 * 8) << 1) ^ ((o & 7) << 4);
        *(int4*)((char*)lB + byte) = v;
    }
    __syncthreads();

    f32x4 acc[MR][NR];
    #pragma unroll
    for (int m = 0; m < MR; ++m)
        #pragma unroll
        for (int n = 0; n < NR; ++n)
            acc[m][n] = (f32x4){0.f, 0.f, 0.f, 0.f};

    #pragma unroll
    for (int kk = 0; kk < BK / 32; ++kk) {
        const int kpos = kk * 32 + (lane >> 4) * 8;
        bf16x8 af[MR], bfr[NR];
        #pragma unroll
        for (int m = 0; m < MR; ++m) {
            int row = wv * 32 + m * 16 + (lane & 15);
            af[m] = *(const bf16x8*)((const char*)lA +
                     (((row * BK + kpos) << 1) ^ ((row & 7) << 4)));
        }
        #pragma unroll
        for (int n = 0; n < NR; ++n) {
            int col = n * 16 + (lane & 15);
            bfr[n] = *(const bf16x8*)((const char*)lB +
                     (((col * BK + kpos) << 1) ^ ((col & 7) << 4)));
        }
        #pragma unroll
        for (int m = 0; m < MR; ++m)
            #pragma unroll
            for (int n = 0; n < NR; ++n)
                acc[m][n] = __builtin_amdgcn_mfma_f32_16x16x32_bf16(
                    af[m], bfr[n], acc[m][n], 0, 0, 0);
    }

    #pragma unroll
    for (int m = 0; m < MR; ++m)
        #pragma unroll
        for (int n = 0; n < NR; ++n)
            #pragma unroll
            for (int i = 0; i < 4; ++i) {
                int row  = wv * 32 + m * 16 + ((lane >> 4) << 2) + i;
                int col  = n * 16 + (lane & 15);
                int grow = nodeBase + row;
                if (grow >= N) continue;
                int gcol = colBase + col;
                out[(size_t)grow * DADR + gcol] = acc[m][n][i] + bc[gcol];
            }
}

static inline size_t align16(size_t x) { return (x + 15) & ~(size_t)15; }

extern "C" void kernel_launch(void* const* d_in, const int* in_sizes, int n_in,
                              void* d_out, int out_size, void* d_ws, size_t ws_size,
                              hipStream_t stream) {
    const float* x      = (const float*)d_in[0];
    const int*   ei     = (const int*)d_in[1];
    const int*   et     = (const int*)d_in[2];
    const float* comp1  = (const float*)d_in[3];
    const float* basis1 = (const float*)d_in[4];
    const float* root1  = (const float*)d_in[5];
    const float* bias1  = (const float*)d_in[6];
    const float* comp2  = (const float*)d_in[7];
    const float* basis2 = (const float*)d_in[8];
    const float* root2  = (const float*)d_in[9];
    const float* bias2  = (const float*)d_in[10];
    const float* wc     = (const float*)d_in[11];
    const float* bc     = (const float*)d_in[12];
    float* out = (float*)d_out;

    const int E = in_sizes[1] / 2;
    const int N = in_sizes[0] / DIN1;
    const int* srcp = ei;
    const int* dstp = ei + E;

    const int NSEG = N * R_;
    const int NBLK = (NSEG + SCAN_CHUNK - 1) / SCAN_CHUNK;

    char* ws = (char*)d_ws;
    size_t o = 0;
    int*   cntI   = (int*)(ws + o);   o = align16(o + (size_t)NSEG * 4);
    int*   off2   = (int*)(ws + o);   o = align16(o + (size_t)(NSEG + 1) * 4);
    int*   cursor = (int*)(ws + o);   o = align16(o + (size_t)NSEG * 4);
    int*   bsum   = (int*)(ws + o);   o = align16(o + (size_t)NBLK * 4);
    int*   boff   = (int*)(ws + o);   o = align16(o + (size_t)NBLK * 4);
    int*   srt    = (int*)(ws + o);   o = align16(o + (size_t)E * 4);
    short* BT1    = (short*)(ws + o); o = align16(o + (size_t)(R_ + 1) * DHID * 128 * 2);
    short* BT2    = (short*)(ws + o); o = align16(o + (size_t)(R_ + 1) * DOUT2 * 128 * 2);
    short* wcTb   = (short*)(ws + o); o = align16(o + (size_t)DADR * DOUT2 * 2);
    short* xbf    = (short*)(ws + o); o = align16(o + (size_t)N * DIN1 * 2);
    short* h1bf   = (short*)(ws + o); o = align16(o + (size_t)N * DHID * 2);
    short* h2bf   = (short*)(ws + o); o = align16(o + (size_t)N * DOUT2 * 2);

    // ---- fused setup: tobf + counts + weight prep ----
    const int n4 = N * DIN1 / 4;
    hipMemsetAsync(cntI, 0, (size_t)NSEG * 4, stream);
    {
        long long total = (long long)n4 + E + PREP5;
        int grid = (int)((total + 255) / 256);
        setup_kernel<<<grid, 256, 0, stream>>>(x, xbf, n4, dstp, et, cntI, E, N,
                                               comp1, basis1, root1,
                                               comp2, basis2, root2, wc,
                                               BT1, BT2, wcTb);
    }

    // ---- CSR scan + reorder ----
    scan_bsum_kernel<<<NBLK, 256, 0, stream>>>(cntI, NSEG, bsum);
    scan_top_kernel<<<1, 256, 0, stream>>>(bsum, NBLK, boff, off2, NSEG);
    scan_final_kernel<<<NBLK, 256, 0, stream>>>(cntI, NSEG, boff, off2, cursor);
    reorder_kernel<<<(E + 255) / 256, 256, 0, stream>>>(srcp, dstp, et, cursor, srt, E, N);

    // ---- two fused RGCN layers ----
    const int gGrid = (N + 31) / 32;
    rgcn_fused_kernel<DHID, true><<<gGrid, 256, 0, stream>>>(xbf,  off2, srt, BT1, bias1, h1bf, N, 1);
    rgcn_fused_kernel<DOUT2, true><<<gGrid, 256, 0, stream>>>(h1bf, off2, srt, BT2, bias2, h2bf, N, 0);

    // ---- classifier (MFMA) ----
    dim3 cGrid((N + 127) / 128, DADR / 80);
    classifier_gemm_kernel<<<cGrid, 256, 0, stream>>>(h2bf, wcTb, bc, out, N);
}